// Round 1
// baseline (150.484 us; speedup 1.0000x reference)
//
#include <hip/hip_runtime.h>

#define BINS 10
#define BLOCK 256
#define GRID 2048

// ---------------------------------------------------------------------------
// Pass 1: fused histogram + per-bin smooth-L1 loss sums.
// Per-thread register accumulators (compile-time indexed), wave shuffle
// reduce, LDS block reduce, global atomics (f32 counts exact as integers
// < 2^24; loss sums in f64).
// ---------------------------------------------------------------------------
__global__ __launch_bounds__(BLOCK) void ghmr_histo_kernel(
    const float* __restrict__ pred,
    const float* __restrict__ target,
    double* __restrict__ g_sum,   // [BINS] f64, pre-zeroed
    float*  __restrict__ g_cnt,   // [BINS] f32, pre-zeroed
    int n)
{
    float c[BINS];
    float s[BINS];
#pragma unroll
    for (int b = 0; b < BINS; ++b) { c[b] = 0.0f; s[b] = 0.0f; }

    const int tid    = blockIdx.x * BLOCK + threadIdx.x;
    const int stride = gridDim.x * BLOCK;
    const int n4     = n >> 2;

    const float4* p4 = reinterpret_cast<const float4*>(pred);
    const float4* t4 = reinterpret_cast<const float4*>(target);

    for (int i = tid; i < n4; i += stride) {
        float4 p = p4[i];
        float4 t = t4[i];
        float pe[4] = {p.x, p.y, p.z, p.w};
        float te[4] = {t.x, t.y, t.z, t.w};
#pragma unroll
        for (int k = 0; k < 4; ++k) {
            float d  = pe[k] - te[k];
            float ad = fabsf(d);
            // wrapped angular diff -> [0,180], normalized
            float wd = fminf(ad, 360.0f - ad);
            float g  = wd / 180.0f;                 // match ref: true divide
            int idx  = (int)floorf(g * 10.0f);
            idx = min(max(idx, 0), BINS - 1);
            // smooth L1, beta = MU = 1
            float ls = (ad < 1.0f) ? (0.5f * d * d) : (ad - 0.5f);
#pragma unroll
            for (int b = 0; b < BINS; ++b) {
                bool m = (idx == b);
                c[b] += m ? 1.0f : 0.0f;
                s[b] += m ? ls   : 0.0f;
            }
        }
    }
    // scalar tail (n % 4), generic safety
    for (int i = (n4 << 2) + tid; i < n; i += stride) {
        float d  = pred[i] - target[i];
        float ad = fabsf(d);
        float wd = fminf(ad, 360.0f - ad);
        float g  = wd / 180.0f;
        int idx  = (int)floorf(g * 10.0f);
        idx = min(max(idx, 0), BINS - 1);
        float ls = (ad < 1.0f) ? (0.5f * d * d) : (ad - 0.5f);
#pragma unroll
        for (int b = 0; b < BINS; ++b) {
            bool m = (idx == b);
            c[b] += m ? 1.0f : 0.0f;
            s[b] += m ? ls   : 0.0f;
        }
    }

    // wave(64) butterfly reduce, all indices compile-time
#pragma unroll
    for (int b = 0; b < BINS; ++b) {
#pragma unroll
        for (int off = 32; off > 0; off >>= 1) {
            c[b] += __shfl_down(c[b], off, 64);
            s[b] += __shfl_down(s[b], off, 64);
        }
    }

    __shared__ float lc[BINS];
    __shared__ float lsum[BINS];
    if (threadIdx.x < BINS) { lc[threadIdx.x] = 0.0f; lsum[threadIdx.x] = 0.0f; }
    __syncthreads();
    if ((threadIdx.x & 63) == 0) {   // lane 0 of each of the 4 waves
#pragma unroll
        for (int b = 0; b < BINS; ++b) {
            atomicAdd(&lc[b], c[b]);
            atomicAdd(&lsum[b], s[b]);
        }
    }
    __syncthreads();
    if (threadIdx.x < BINS) {
        atomicAdd(&g_cnt[threadIdx.x], lc[threadIdx.x]);
        atomicAdd(&g_sum[threadIdx.x], (double)lsum[threadIdx.x]);
    }
}

// ---------------------------------------------------------------------------
// Pass 2: tiny finalize — 10-bin weight math + final scalar. One thread.
// ---------------------------------------------------------------------------
__global__ void ghmr_final_kernel(
    const double* __restrict__ g_sum,
    const float*  __restrict__ g_cnt,
    const float*  __restrict__ acc_sum,
    float* __restrict__ out,
    float total)
{
    if (threadIdx.x != 0 || blockIdx.x != 0) return;

    float acc_new[BINS];
    int n_nonempty = 0;
#pragma unroll
    for (int b = 0; b < BINS; ++b) {
        float cnt = g_cnt[b];
        bool ne = (cnt > 0.0f);
        acc_new[b] = ne ? (0.9f * acc_sum[b] + 0.1f * cnt) : acc_sum[b];
        n_nonempty += ne ? 1 : 0;
    }
    float n_safe = fmaxf((float)n_nonempty, 1.0f);

    double weighted = 0.0;
    double plain    = 0.0;
#pragma unroll
    for (int b = 0; b < BINS; ++b) {
        float wb = (acc_new[b] > 0.0f)
                       ? (total / (n_safe * fmaxf(acc_new[b], 1e-30f)))
                       : 0.0f;
        float wp = powf(wb, 0.75f);
        weighted += g_sum[b] * (double)wp;
        plain    += g_sum[b];
    }
    double res = ((n_nonempty > 0) ? weighted : plain) / (double)total;
    out[0] = (float)res;
}

extern "C" void kernel_launch(void* const* d_in, const int* in_sizes, int n_in,
                              void* d_out, int out_size, void* d_ws, size_t ws_size,
                              hipStream_t stream) {
    const float* pred    = (const float*)d_in[0];
    const float* target  = (const float*)d_in[1];
    const float* acc_sum = (const float*)d_in[2];
    float* out = (float*)d_out;
    const int n = in_sizes[0];

    // workspace layout: [0,80) f64 loss sums, [80,120) f32 counts
    double* g_sum = (double*)d_ws;
    float*  g_cnt = (float*)((char*)d_ws + BINS * sizeof(double));
    hipMemsetAsync(d_ws, 0, 128, stream);

    ghmr_histo_kernel<<<GRID, BLOCK, 0, stream>>>(pred, target, g_sum, g_cnt, n);
    ghmr_final_kernel<<<1, 64, 0, stream>>>(g_sum, g_cnt, acc_sum, out, (float)n);
}

// Round 2
// 114.026 us; speedup vs baseline: 1.3197x; 1.3197x over previous
//
#include <hip/hip_runtime.h>

#define BINS 10
#define BLOCK 256
#define GRID 2048

// ---------------------------------------------------------------------------
// Pass 1: fused histogram + per-bin smooth-L1 loss sums.
// Per-thread register accumulators (compile-time indexed), wave shuffle
// reduce, LDS cross-wave combine, then NON-ATOMIC per-block partial stores
// to d_ws (layout [bin][block]). No global atomics -> no same-address
// serialization.
// ---------------------------------------------------------------------------
__global__ __launch_bounds__(BLOCK) void ghmr_histo_kernel(
    const float* __restrict__ pred,
    const float* __restrict__ target,
    float* __restrict__ part_cnt,   // [BINS][nblk]
    float* __restrict__ part_sum,   // [BINS][nblk]
    int n)
{
    float c[BINS];
    float s[BINS];
#pragma unroll
    for (int b = 0; b < BINS; ++b) { c[b] = 0.0f; s[b] = 0.0f; }

    const int tid    = blockIdx.x * BLOCK + threadIdx.x;
    const int stride = gridDim.x * BLOCK;
    const int n4     = n >> 2;

    const float4* p4 = reinterpret_cast<const float4*>(pred);
    const float4* t4 = reinterpret_cast<const float4*>(target);

    for (int i = tid; i < n4; i += stride) {
        float4 p = p4[i];
        float4 t = t4[i];
        float pe[4] = {p.x, p.y, p.z, p.w};
        float te[4] = {t.x, t.y, t.z, t.w};
#pragma unroll
        for (int k = 0; k < 4; ++k) {
            float d  = pe[k] - te[k];
            float ad = fabsf(d);
            // wrapped angular diff -> [0,180], normalized
            float wd = fminf(ad, 360.0f - ad);
            float g  = wd / 180.0f;                 // match ref exactly
            int idx  = (int)floorf(g * 10.0f);
            idx = min(max(idx, 0), BINS - 1);
            // smooth L1, beta = MU = 1
            float ls = (ad < 1.0f) ? (0.5f * d * d) : (ad - 0.5f);
#pragma unroll
            for (int b = 0; b < BINS; ++b) {
                float mf = (idx == b) ? 1.0f : 0.0f;   // cmp + cndmask
                c[b] += mf;                             // add
                s[b] = fmaf(mf, ls, s[b]);              // fma
            }
        }
    }
    // scalar tail (n % 4), generic safety
    for (int i = (n4 << 2) + tid; i < n; i += stride) {
        float d  = pred[i] - target[i];
        float ad = fabsf(d);
        float wd = fminf(ad, 360.0f - ad);
        float g  = wd / 180.0f;
        int idx  = (int)floorf(g * 10.0f);
        idx = min(max(idx, 0), BINS - 1);
        float ls = (ad < 1.0f) ? (0.5f * d * d) : (ad - 0.5f);
#pragma unroll
        for (int b = 0; b < BINS; ++b) {
            float mf = (idx == b) ? 1.0f : 0.0f;
            c[b] += mf;
            s[b] = fmaf(mf, ls, s[b]);
        }
    }

    // wave(64) butterfly reduce, compile-time indices only
#pragma unroll
    for (int b = 0; b < BINS; ++b) {
#pragma unroll
        for (int off = 32; off > 0; off >>= 1) {
            c[b] += __shfl_down(c[b], off, 64);
            s[b] += __shfl_down(s[b], off, 64);
        }
    }

    // cross-wave combine in LDS: 4 waves per block
    __shared__ float lc[4][BINS];
    __shared__ float ls_[4][BINS];
    const int wave = threadIdx.x >> 6;
    const int lane = threadIdx.x & 63;
    if (lane == 0) {
#pragma unroll
        for (int b = 0; b < BINS; ++b) { lc[wave][b] = c[b]; ls_[wave][b] = s[b]; }
    }
    __syncthreads();
    if (threadIdx.x < BINS) {
        const int b = threadIdx.x;
        float cb = lc[0][b] + lc[1][b] + lc[2][b] + lc[3][b];
        float sb = ls_[0][b] + ls_[1][b] + ls_[2][b] + ls_[3][b];
        part_cnt[b * gridDim.x + blockIdx.x] = cb;
        part_sum[b * gridDim.x + blockIdx.x] = sb;
    }
}

// ---------------------------------------------------------------------------
// Pass 2: reduce partials (one wave per bin, coalesced) + weight math + out.
// ---------------------------------------------------------------------------
__global__ __launch_bounds__(64 * BINS) void ghmr_reduce_final(
    const float* __restrict__ part_cnt,
    const float* __restrict__ part_sum,
    const float* __restrict__ acc_sum,
    float* __restrict__ out,
    float total, int nblk)
{
    const int wave = threadIdx.x >> 6;   // 0..BINS-1
    const int lane = threadIdx.x & 63;

    float csum = 0.0f, ssum = 0.0f;
    const float* pc = part_cnt + wave * nblk;
    const float* ps = part_sum + wave * nblk;
    for (int i = lane; i < nblk; i += 64) { csum += pc[i]; ssum += ps[i]; }
#pragma unroll
    for (int off = 32; off > 0; off >>= 1) {
        csum += __shfl_down(csum, off, 64);
        ssum += __shfl_down(ssum, off, 64);
    }

    __shared__ float C[BINS];
    __shared__ float S[BINS];
    if (lane == 0) { C[wave] = csum; S[wave] = ssum; }
    __syncthreads();

    if (threadIdx.x == 0) {
        float acc_new[BINS];
        int n_nonempty = 0;
#pragma unroll
        for (int b = 0; b < BINS; ++b) {
            float cnt = C[b];
            bool ne = (cnt > 0.0f);
            acc_new[b] = ne ? (0.9f * acc_sum[b] + 0.1f * cnt) : acc_sum[b];
            n_nonempty += ne ? 1 : 0;
        }
        float n_safe = fmaxf((float)n_nonempty, 1.0f);

        double weighted = 0.0;
        double plain    = 0.0;
#pragma unroll
        for (int b = 0; b < BINS; ++b) {
            float wb = (acc_new[b] > 0.0f)
                           ? (total / (n_safe * fmaxf(acc_new[b], 1e-30f)))
                           : 0.0f;
            float wp = powf(wb, 0.75f);
            weighted += (double)S[b] * (double)wp;
            plain    += (double)S[b];
        }
        double res = ((n_nonempty > 0) ? weighted : plain) / (double)total;
        out[0] = (float)res;
    }
}

extern "C" void kernel_launch(void* const* d_in, const int* in_sizes, int n_in,
                              void* d_out, int out_size, void* d_ws, size_t ws_size,
                              hipStream_t stream) {
    const float* pred    = (const float*)d_in[0];
    const float* target  = (const float*)d_in[1];
    const float* acc_sum = (const float*)d_in[2];
    float* out = (float*)d_out;
    const int n = in_sizes[0];

    int nblk = GRID;
    size_t need = (size_t)2 * BINS * (size_t)nblk * sizeof(float);
    if (ws_size < need) {
        nblk = (int)(ws_size / ((size_t)2 * BINS * sizeof(float)));
        if (nblk < 1) nblk = 1;
    }

    float* part_cnt = (float*)d_ws;                     // [BINS][nblk]
    float* part_sum = part_cnt + (size_t)BINS * nblk;   // [BINS][nblk]

    ghmr_histo_kernel<<<nblk, BLOCK, 0, stream>>>(pred, target, part_cnt, part_sum, n);
    ghmr_reduce_final<<<1, 64 * BINS, 0, stream>>>(part_cnt, part_sum, acc_sum, out,
                                                   (float)n, nblk);
}

// Round 3
// 102.193 us; speedup vs baseline: 1.4725x; 1.1158x over previous
//
#include <hip/hip_runtime.h>

#define BINS 10
#define BLOCK 256
#define GRID 1024

// ---------------------------------------------------------------------------
// Pass 1: fused histogram + per-bin smooth-L1 loss sums.
// LDS per-thread-column histogram: h[bin][tid] = float2{count, loss_sum}.
// Each thread owns column tid -> no conflicts, no atomics. RMW per element:
// ds_read_b64 + 2 VALU adds + ds_write_b64 (in-order DS pipe makes
// same-bin consecutive RMWs safe). Epilogue: 160 threads reduce 10 rows.
// ---------------------------------------------------------------------------
__global__ __launch_bounds__(BLOCK) void ghmr_histo_kernel(
    const float* __restrict__ pred,
    const float* __restrict__ target,
    float2* __restrict__ part,   // [BINS][nblk] {cnt, sum}
    int n)
{
    __shared__ float2 h[BINS][BLOCK];
    const int t = threadIdx.x;
#pragma unroll
    for (int b = 0; b < BINS; ++b) h[b][t] = make_float2(0.0f, 0.0f);
    __syncthreads();

    const float INV180 = 1.0f / 180.0f;   // mul, not div (<=1ulp vs ref divide)
    const int tid    = blockIdx.x * BLOCK + t;
    const int stride = gridDim.x * BLOCK;
    const int n4     = n >> 2;

    const float4* p4 = reinterpret_cast<const float4*>(pred);
    const float4* t4 = reinterpret_cast<const float4*>(target);

    for (int i = tid; i < n4; i += stride) {
        float4 p = p4[i];
        float4 q = t4[i];
        float pe[4] = {p.x, p.y, p.z, p.w};
        float te[4] = {q.x, q.y, q.z, q.w};
#pragma unroll
        for (int k = 0; k < 4; ++k) {
            float d  = pe[k] - te[k];
            float ad = fabsf(d);
            float wd = fminf(ad, 360.0f - ad);   // wrapped to [0,180]
            float g  = wd * INV180;              // ref: diff/180
            float gg = g * 10.0f;                // ref: g*BINS
            int idx  = (int)gg;                  // gg>=0 -> trunc == floor
            idx = min(max(idx, 0), BINS - 1);
            float ls = (ad < 1.0f) ? (0.5f * d * d) : (ad - 0.5f);  // smooth L1, mu=1
            float2 v = h[idx][t];
            v.x += 1.0f;
            v.y += ls;
            h[idx][t] = v;
        }
    }
    // scalar tail (n % 4), generic safety
    for (int i = (n4 << 2) + tid; i < n; i += stride) {
        float d  = pred[i] - target[i];
        float ad = fabsf(d);
        float wd = fminf(ad, 360.0f - ad);
        float g  = wd * INV180;
        float gg = g * 10.0f;
        int idx  = (int)gg;
        idx = min(max(idx, 0), BINS - 1);
        float ls = (ad < 1.0f) ? (0.5f * d * d) : (ad - 0.5f);
        float2 v = h[idx][t];
        v.x += 1.0f;
        v.y += ls;
        h[idx][t] = v;
    }
    __syncthreads();

    // Block epilogue: 160 threads, thread (r=t>>4, j=t&15) sums 16 columns
    // stride-16, then 16-lane-group shuffle tree. One float2 store per bin.
    if (t < 16 * BINS) {
        const int r = t >> 4;
        const int j = t & 15;
        float c = 0.0f, s = 0.0f;
#pragma unroll
        for (int k = 0; k < 16; ++k) {
            float2 v = h[r][j + 16 * k];
            c += v.x;
            s += v.y;
        }
#pragma unroll
        for (int off = 8; off > 0; off >>= 1) {
            c += __shfl_down(c, off, 16);
            s += __shfl_down(s, off, 16);
        }
        if (j == 0) part[r * gridDim.x + blockIdx.x] = make_float2(c, s);
    }
}

// ---------------------------------------------------------------------------
// Pass 2: reduce partials (one wave per bin, coalesced float2) + weight math.
// ---------------------------------------------------------------------------
__global__ __launch_bounds__(64 * BINS) void ghmr_reduce_final(
    const float2* __restrict__ part,
    const float*  __restrict__ acc_sum,
    float* __restrict__ out,
    float total, int nblk)
{
    const int w    = threadIdx.x >> 6;   // bin 0..9
    const int lane = threadIdx.x & 63;

    float csum = 0.0f, ssum = 0.0f;
    const float2* pw = part + (size_t)w * nblk;
    for (int i = lane; i < nblk; i += 64) {
        float2 v = pw[i];
        csum += v.x;
        ssum += v.y;
    }
#pragma unroll
    for (int off = 32; off > 0; off >>= 1) {
        csum += __shfl_down(csum, off, 64);
        ssum += __shfl_down(ssum, off, 64);
    }

    __shared__ float C[BINS];
    __shared__ float S[BINS];
    if (lane == 0) { C[w] = csum; S[w] = ssum; }
    __syncthreads();

    if (threadIdx.x == 0) {
        float acc_new[BINS];
        int n_nonempty = 0;
#pragma unroll
        for (int b = 0; b < BINS; ++b) {
            float cnt = C[b];
            bool ne = (cnt > 0.0f);
            acc_new[b] = ne ? (0.9f * acc_sum[b] + 0.1f * cnt) : acc_sum[b];
            n_nonempty += ne ? 1 : 0;
        }
        float n_safe = fmaxf((float)n_nonempty, 1.0f);

        double weighted = 0.0;
        double plain    = 0.0;
#pragma unroll
        for (int b = 0; b < BINS; ++b) {
            float wb = (acc_new[b] > 0.0f)
                           ? (total / (n_safe * fmaxf(acc_new[b], 1e-30f)))
                           : 0.0f;
            float wp = powf(wb, 0.75f);
            weighted += (double)S[b] * (double)wp;
            plain    += (double)S[b];
        }
        double res = ((n_nonempty > 0) ? weighted : plain) / (double)total;
        out[0] = (float)res;
    }
}

extern "C" void kernel_launch(void* const* d_in, const int* in_sizes, int n_in,
                              void* d_out, int out_size, void* d_ws, size_t ws_size,
                              hipStream_t stream) {
    const float* pred    = (const float*)d_in[0];
    const float* target  = (const float*)d_in[1];
    const float* acc_sum = (const float*)d_in[2];
    float* out = (float*)d_out;
    const int n = in_sizes[0];

    int nblk = GRID;
    size_t need = (size_t)BINS * (size_t)nblk * sizeof(float2);
    if (ws_size < need) {
        nblk = (int)(ws_size / ((size_t)BINS * sizeof(float2)));
        if (nblk < 1) nblk = 1;
    }

    float2* part = (float2*)d_ws;   // [BINS][nblk]

    ghmr_histo_kernel<<<nblk, BLOCK, 0, stream>>>(pred, target, part, n);
    ghmr_reduce_final<<<1, 64 * BINS, 0, stream>>>(part, acc_sum, out, (float)n, nblk);
}